// Round 4
// baseline (213.377 us; speedup 1.0000x reference)
//
#include <hip/hip_runtime.h>

// SpikingNeuralNetwork: fc1 (split-bf16x3 MFMA GEMM, fused LIF scan) + sparse fc2.
// R4: 2 phases/K-tile (4 barriers, was 8), uniform counted vmcnt(4) never-drain,
// scanbuf padded stride 260. 256x256 tile, 32x32x16 MFMA, dbuf LDS, setprio.

typedef __attribute__((ext_vector_type(16))) float f32x16;
typedef __attribute__((ext_vector_type(8))) short s16x8;

#define GPTR(p) ((const __attribute__((address_space(1))) void*)(p))
#define SPTR(p) ((__attribute__((address_space(3))) void*)(p))

static constexpr int Bsz = 64, Tsz = 256, Isz = 1024, Hsz = 2048, Osz = 1024;
static constexpr int BK = 32;          // fp32-k per K-tile
static constexpr int NKT = Isz / BK;   // 32
// buffer regions (ushort elements): Ah, Al, Bh, Bl each 256x32
static constexpr int AH_OFF = 0, AL_OFF = 8192, BH_OFF = 16384, BL_OFF = 24576;
static constexpr int BUFEL = 32768;    // 64KB per K-tile buffer, x2 = 128KB
static constexpr int SCAN_STRIDE = 260;  // padded f32 stride (bank spread)
// LDS union: max(2*BUFEL ushorts = 128KB, 128*260*4B = 133.1KB)
static constexpr int LDS_USHORTS = 128 * SCAN_STRIDE * 2;  // 66560 -> 133120 B

__device__ __forceinline__ unsigned short f2bf(float f) {
  unsigned u = __float_as_uint(f);
  u += 0x7FFFu + ((u >> 16) & 1u);
  return (unsigned short)(u >> 16);
}
__device__ __forceinline__ float bf2f(unsigned short h) {
  return __uint_as_float(((unsigned)h) << 16);
}

// ---------------- kernel 1: split x into hi/lo bf16 ----------------
__global__ void split_x_kernel(const float* __restrict__ x,
                               unsigned short* __restrict__ hi,
                               unsigned short* __restrict__ lo) {
  const long i = (long)blockIdx.x * 256 + threadIdx.x;
  const float4 v = ((const float4*)x)[i];
  const unsigned short hx = f2bf(v.x), hy = f2bf(v.y), hz = f2bf(v.z), hw = f2bf(v.w);
  ushort4 H, L;
  H.x = hx; H.y = hy; H.z = hz; H.w = hw;
  L.x = f2bf(v.x - bf2f(hx));
  L.y = f2bf(v.y - bf2f(hy));
  L.z = f2bf(v.z - bf2f(hz));
  L.w = f2bf(v.w - bf2f(hw));
  ((ushort4*)hi)[i] = H;
  ((ushort4*)lo)[i] = L;
}

// ------- kernel 2: W1 [I][H] -> transposed bf16 hi/lo [H][I] -------
__global__ void w1_transpose_split_kernel(const float* __restrict__ W1,
                                          unsigned short* __restrict__ wh,
                                          unsigned short* __restrict__ wl) {
  __shared__ float tile[32][33];
  const int h0 = blockIdx.x * 32;
  const int i0 = blockIdx.y * 32;
  const int c = threadIdx.x & 31;
  const int r4 = threadIdx.x >> 5;
#pragma unroll
  for (int s = 0; s < 4; ++s) {
    const int r = r4 + s * 8;
    tile[r][c] = W1[(long)(i0 + r) * Hsz + h0 + c];
  }
  __syncthreads();
#pragma unroll
  for (int s = 0; s < 4; ++s) {
    const int hr = r4 + s * 8;
    const float v = tile[c][hr];
    const unsigned short hh = f2bf(v);
    wh[(long)(h0 + hr) * Isz + i0 + c] = hh;
    wl[(long)(h0 + hr) * Isz + i0 + c] = f2bf(v - bf2f(hh));
  }
}

// ---- kernel 3: fused GEMM1 (split-bf16x3, 32x32x16 MFMA) + LIF scan ----
// grid (8 hblk, 64 b), 512 threads = 8 waves (2M x 4N); wave tile 128x64.
__global__ __launch_bounds__(512, 2) void gemm1_scan_kernel(
    const unsigned short* __restrict__ xh, const unsigned short* __restrict__ xl,
    const unsigned short* __restrict__ wth, const unsigned short* __restrict__ wtl,
    const float* __restrict__ b1, float* __restrict__ spk) {
  __shared__ __align__(16) unsigned short lds[LDS_USHORTS];  // 133.1KB

  const int tid = threadIdx.x;
  const int l = tid & 63;
  const int w = tid >> 6;
  const int wm = w >> 2;  // 0..1 (M: t rows)
  const int wn = w & 3;   // 0..3 (N: h cols)
  const int b = blockIdx.y;
  const int hb = blockIdx.x * 256;

  // --- staging source addressing (linear LDS dest + inverse-swizzled source) ---
  // LDS row = 32 ushort = 64B = 4 chunks of 16B; stored chunk' = chunk ^ ((row>>1)&3)
  const int srow = tid >> 2;                          // 0..127
  const int gch8 = ((tid & 3) ^ ((tid >> 3) & 3)) * 8;
  const long aoff0 = (long)(b * Tsz + srow) * Isz + gch8;
  const long aoff1 = (long)(b * Tsz + 128 + srow) * Isz + gch8;
  const long boff0 = (long)(hb + srow) * Isz + gch8;
  const long boff1 = (long)(hb + 128 + srow) * Isz + gch8;
  const unsigned short* gAh0 = xh + aoff0;  const unsigned short* gAh1 = xh + aoff1;
  const unsigned short* gAl0 = xl + aoff0;  const unsigned short* gAl1 = xl + aoff1;
  const unsigned short* gBh0 = wth + boff0; const unsigned short* gBh1 = wth + boff1;
  const unsigned short* gBl0 = wtl + boff0; const unsigned short* gBl1 = wtl + boff1;

#define STG(OFF, G0, G1, KT) do {                                                      \
    unsigned short* d_ = lds + ((KT) & 1) * BUFEL + (OFF) + tid * 8;                   \
    __builtin_amdgcn_global_load_lds(GPTR((G0) + (long)(KT) * BK), SPTR(d_), 16, 0, 0);\
    __builtin_amdgcn_global_load_lds(GPTR((G1) + (long)(KT) * BK), SPTR(d_ + 4096), 16, 0, 0); \
  } while (0)

  // --- fragment read addressing (swizzled): A row = wm*128+mi*32+(l&31), k = ks*16+(l>>5)*8+j
  const int lr = l & 31;
  const int swzf = (l >> 1) & 3;
  const int chK0 = (((l >> 5)) ^ swzf) * 8;      // ks=0 chunk
  const int chK1 = ((2 + (l >> 5)) ^ swzf) * 8;  // ks=1 chunk
  const int abase = (wm * 128 + lr) * 32;
  const int bbase = (wn * 64 + lr) * 32;

  f32x16 acc[4][2];
#pragma unroll
  for (int i = 0; i < 4; ++i)
#pragma unroll
    for (int j = 0; j < 2; ++j) acc[i][j] = (f32x16)(0.f);

#define MM(MI, NI, AF, BF) \
  acc[MI][NI] = __builtin_amdgcn_mfma_f32_32x32x16_bf16(AF, BF, acc[MI][NI], 0, 0, 0)

#define BAR() __builtin_amdgcn_s_barrier()
#define LGKM0() do { asm volatile("s_waitcnt lgkmcnt(0)" ::: "memory");                \
    __builtin_amdgcn_sched_barrier(0); } while (0)

  // --- prologue: stage tile 0 fully, drain once ---
  STG(AH_OFF, gAh0, gAh1, 0);
  STG(BH_OFF, gBh0, gBh1, 0);
  STG(AL_OFF, gAl0, gAl1, 0);
  STG(BL_OFF, gBl0, gBl1, 0);
  asm volatile("s_waitcnt vmcnt(0)" ::: "memory");
  BAR();

  s16x8 Ah0[4], Ah1[4], Al0[4], Al1[4], Bh0[2], Bh1[2], Bl0[2], Bl1[2];

  for (int kt = 0; kt < NKT; ++kt) {
    const unsigned short* p = lds + (kt & 1) * BUFEL;
    const bool st = (kt + 1) < NKT;

    // ======== phase A: read Ah(ks0,ks1)+Bh(ks0,ks1); stage AH,BH(kt+1); 16 MFMA hihi ========
#pragma unroll
    for (int mi = 0; mi < 4; ++mi) {
      Ah0[mi] = *(const s16x8*)(p + AH_OFF + abase + mi * 1024 + chK0);
      Ah1[mi] = *(const s16x8*)(p + AH_OFF + abase + mi * 1024 + chK1);
    }
#pragma unroll
    for (int ni = 0; ni < 2; ++ni) {
      Bh0[ni] = *(const s16x8*)(p + BH_OFF + bbase + ni * 1024 + chK0);
      Bh1[ni] = *(const s16x8*)(p + BH_OFF + bbase + ni * 1024 + chK1);
    }
    if (st) { STG(AH_OFF, gAh0, gAh1, kt + 1); STG(BH_OFF, gBh0, gBh1, kt + 1); }
    BAR();
    LGKM0();
    __builtin_amdgcn_s_setprio(1);
    MM(0, 0, Ah0[0], Bh0[0]); MM(0, 1, Ah0[0], Bh0[1]);
    MM(1, 0, Ah0[1], Bh0[0]); MM(1, 1, Ah0[1], Bh0[1]);
    MM(2, 0, Ah0[2], Bh0[0]); MM(2, 1, Ah0[2], Bh0[1]);
    MM(3, 0, Ah0[3], Bh0[0]); MM(3, 1, Ah0[3], Bh0[1]);
    MM(0, 0, Ah1[0], Bh1[0]); MM(0, 1, Ah1[0], Bh1[1]);
    MM(1, 0, Ah1[1], Bh1[0]); MM(1, 1, Ah1[1], Bh1[1]);
    MM(2, 0, Ah1[2], Bh1[0]); MM(2, 1, Ah1[2], Bh1[1]);
    MM(3, 0, Ah1[3], Bh1[0]); MM(3, 1, Ah1[3], Bh1[1]);
    __builtin_amdgcn_s_setprio(0);
    // outstanding: AL,BL(kt)[4 oldest] + AH,BH(kt+1)[4] -> need AL,BL(kt) for phase B
    if (st) asm volatile("s_waitcnt vmcnt(4)" ::: "memory");
    else    asm volatile("s_waitcnt vmcnt(0)" ::: "memory");  // kt=31: only AL,BL(31) left
    BAR();

    // ======== phase B: read Al+Bl; stage AL,BL(kt+1); 32 MFMA (hilo + lohi) ========
#pragma unroll
    for (int mi = 0; mi < 4; ++mi) {
      Al0[mi] = *(const s16x8*)(p + AL_OFF + abase + mi * 1024 + chK0);
      Al1[mi] = *(const s16x8*)(p + AL_OFF + abase + mi * 1024 + chK1);
    }
#pragma unroll
    for (int ni = 0; ni < 2; ++ni) {
      Bl0[ni] = *(const s16x8*)(p + BL_OFF + bbase + ni * 1024 + chK0);
      Bl1[ni] = *(const s16x8*)(p + BL_OFF + bbase + ni * 1024 + chK1);
    }
    if (st) { STG(AL_OFF, gAl0, gAl1, kt + 1); STG(BL_OFF, gBl0, gBl1, kt + 1); }
    BAR();
    LGKM0();
    __builtin_amdgcn_s_setprio(1);
    // hilo: Ah x Bl
    MM(0, 0, Ah0[0], Bl0[0]); MM(0, 1, Ah0[0], Bl0[1]);
    MM(1, 0, Ah0[1], Bl0[0]); MM(1, 1, Ah0[1], Bl0[1]);
    MM(2, 0, Ah0[2], Bl0[0]); MM(2, 1, Ah0[2], Bl0[1]);
    MM(3, 0, Ah0[3], Bl0[0]); MM(3, 1, Ah0[3], Bl0[1]);
    MM(0, 0, Ah1[0], Bl1[0]); MM(0, 1, Ah1[0], Bl1[1]);
    MM(1, 0, Ah1[1], Bl1[0]); MM(1, 1, Ah1[1], Bl1[1]);
    MM(2, 0, Ah1[2], Bl1[0]); MM(2, 1, Ah1[2], Bl1[1]);
    MM(3, 0, Ah1[3], Bl1[0]); MM(3, 1, Ah1[3], Bl1[1]);
    // lohi: Al x Bh
    MM(0, 0, Al0[0], Bh0[0]); MM(0, 1, Al0[0], Bh0[1]);
    MM(1, 0, Al0[1], Bh0[0]); MM(1, 1, Al0[1], Bh0[1]);
    MM(2, 0, Al0[2], Bh0[0]); MM(2, 1, Al0[2], Bh0[1]);
    MM(3, 0, Al0[3], Bh0[0]); MM(3, 1, Al0[3], Bh0[1]);
    MM(0, 0, Al1[0], Bh1[0]); MM(0, 1, Al1[0], Bh1[1]);
    MM(1, 0, Al1[1], Bh1[0]); MM(1, 1, Al1[1], Bh1[1]);
    MM(2, 0, Al1[2], Bh1[0]); MM(2, 1, Al1[2], Bh1[1]);
    MM(3, 0, Al1[3], Bh1[0]); MM(3, 1, Al1[3], Bh1[1]);
    __builtin_amdgcn_s_setprio(0);
    // outstanding: AH,BH(kt+1)[4 oldest] + AL,BL(kt+1)[4] -> need AH,BH(kt+1) next
    asm volatile("s_waitcnt vmcnt(4)" ::: "memory");  // kt=31: 0 outstanding, no-op
    BAR();
  }

  // ---- LIF scan: 2 rounds x 128 timesteps through LDS (padded stride) ----
  __syncthreads();
  float* scanbuf = reinterpret_cast<float*>(lds);  // [128][260] f32
  float memv = 0.f;
  int fired = 0;
  const float b1v = b1[hb + ((tid < 256) ? tid : 0)];

  for (int rnd = 0; rnd < 2; ++rnd) {
    if (wm == rnd) {
      // C/D 32x32: col(h) = l&31, row(t) = (r&3) + 8*(r>>2) + 4*(l>>5)
#pragma unroll
      for (int mi = 0; mi < 4; ++mi)
#pragma unroll
        for (int ni = 0; ni < 2; ++ni) {
          const int col = wn * 64 + ni * 32 + lr;
#pragma unroll
          for (int r = 0; r < 16; ++r) {
            const int trow = mi * 32 + (r & 3) + 8 * (r >> 2) + 4 * (l >> 5);
            scanbuf[trow * SCAN_STRIDE + col] = acc[mi][ni][r];
          }
        }
    }
    __syncthreads();
    if (tid < 256) {
      for (int t = 0; t < 128; ++t) {
        const float c = scanbuf[t * SCAN_STRIDE + tid] + b1v;
        memv = memv * 0.9f + c * 0.1f;
        fired = memv > 1.0f;
        if (fired) memv = 0.f;
      }
    }
    __syncthreads();
  }
  if (tid < 256) spk[(long)b * Hsz + hb + tid] = fired ? 1.0f : 0.0f;
}

// ------- kernel 4: out = spk @ W2 + b2, exploiting spike sparsity -------
__global__ void gemm2_kernel(const float* __restrict__ spk, const float* __restrict__ W2,
                             const float* __restrict__ b2, float* __restrict__ out) {
  __shared__ int s_cnt[256];
  __shared__ int s_off[257];
  __shared__ int s_list[Hsz];
  const int b = blockIdx.x;
  const int tid = threadIdx.x;
  int hs[8];
  int c = 0;
#pragma unroll
  for (int e = 0; e < 8; ++e) {
    const int h = tid * 8 + e;
    if (spk[(long)b * Hsz + h] > 0.5f) hs[c++] = h;
  }
  s_cnt[tid] = c;
  __syncthreads();
  if (tid == 0) {
    int s = 0;
    for (int i = 0; i < 256; ++i) { s_off[i] = s; s += s_cnt[i]; }
    s_off[256] = s;
  }
  __syncthreads();
  {
    const int base = s_off[tid];
    for (int i = 0; i < c; ++i) s_list[base + i] = hs[i];
  }
  __syncthreads();
  const int total = s_off[256];
#pragma unroll
  for (int q = 0; q < 4; ++q) {
    const int o = q * 256 + tid;
    float v = b2[o];
    for (int i = 0; i < total; ++i) v += W2[(long)s_list[i] * Osz + o];
    out[(long)b * Osz + o] = v;
  }
}

extern "C" void kernel_launch(void* const* d_in, const int* in_sizes, int n_in,
                              void* d_out, int out_size, void* d_ws, size_t ws_size,
                              hipStream_t stream) {
  const float* x = (const float*)d_in[0];
  const float* W1 = (const float*)d_in[1];
  const float* b1 = (const float*)d_in[2];
  const float* W2 = (const float*)d_in[3];
  const float* b2 = (const float*)d_in[4];
  float* out = (float*)d_out;

  unsigned short* xh = (unsigned short*)d_ws;           // [16384][1024] bf16
  unsigned short* xl = xh + (long)Bsz * Tsz * Isz;
  unsigned short* wh = xl + (long)Bsz * Tsz * Isz;      // [2048][1024] (W1^T)
  unsigned short* wl = wh + (long)Hsz * Isz;
  float* spk = (float*)(wl + (long)Hsz * Isz);          // [64][2048]

  split_x_kernel<<<(Bsz * Tsz * Isz) / (256 * 4), 256, 0, stream>>>(x, xh, xl);
  w1_transpose_split_kernel<<<dim3(Hsz / 32, Isz / 32), 256, 0, stream>>>(W1, wh, wl);
  gemm1_scan_kernel<<<dim3(8, 64), 512, 0, stream>>>(xh, xl, wh, wl, b1, spk);
  gemm2_kernel<<<Bsz, 256, 0, stream>>>(spk, W2, b2, out);
}

// Round 6
// 208.957 us; speedup vs baseline: 1.0212x; 1.0212x over previous
//
#include <hip/hip_runtime.h>

// SpikingNeuralNetwork: fc1 (split-bf16x3 MFMA GEMM, fused LIF scan) + sparse fc2.
// R6: R5's 4-wave/128x128 structure with the staging race fixed: every vmcnt is
// paired with s_barrier BEFORE dependent cross-wave LDS reads; Al/Bl reads moved
// to phase 2; intra-wave overlap via counted lgkmcnt(8) split-bursts.

typedef __attribute__((ext_vector_type(16))) float f32x16;
typedef __attribute__((ext_vector_type(8))) short s16x8;

#define GPTR(p) ((const __attribute__((address_space(1))) void*)(p))
#define SPTR(p) ((__attribute__((address_space(3))) void*)(p))

static constexpr int Bsz = 64, Tsz = 256, Isz = 1024, Hsz = 2048, Osz = 1024;
static constexpr int BK = 32;          // fp32-k per K-tile
static constexpr int NKT = Isz / BK;   // 32
// buffer regions (ushort elements): Ah, Al, Bh, Bl each 256x32
static constexpr int AH_OFF = 0, AL_OFF = 8192, BH_OFF = 16384, BL_OFF = 24576;
static constexpr int BUFEL = 32768;    // 64KB per K-tile buffer, x2 = 128KB
static constexpr int SCAN_STRIDE = 260;
static constexpr int LDS_USHORTS = 128 * SCAN_STRIDE * 2;  // 133120 B > 2*BUFEL

__device__ __forceinline__ unsigned short f2bf(float f) {
  unsigned u = __float_as_uint(f);
  u += 0x7FFFu + ((u >> 16) & 1u);
  return (unsigned short)(u >> 16);
}
__device__ __forceinline__ float bf2f(unsigned short h) {
  return __uint_as_float(((unsigned)h) << 16);
}

// ---------------- kernel 1: split x into hi/lo bf16 ----------------
__global__ void split_x_kernel(const float* __restrict__ x,
                               unsigned short* __restrict__ hi,
                               unsigned short* __restrict__ lo) {
  const long i = (long)blockIdx.x * 256 + threadIdx.x;
  const float4 v = ((const float4*)x)[i];
  const unsigned short hx = f2bf(v.x), hy = f2bf(v.y), hz = f2bf(v.z), hw = f2bf(v.w);
  ushort4 H, L;
  H.x = hx; H.y = hy; H.z = hz; H.w = hw;
  L.x = f2bf(v.x - bf2f(hx));
  L.y = f2bf(v.y - bf2f(hy));
  L.z = f2bf(v.z - bf2f(hz));
  L.w = f2bf(v.w - bf2f(hw));
  ((ushort4*)hi)[i] = H;
  ((ushort4*)lo)[i] = L;
}

// ------- kernel 2: W1 [I][H] -> transposed bf16 hi/lo [H][I] -------
__global__ void w1_transpose_split_kernel(const float* __restrict__ W1,
                                          unsigned short* __restrict__ wh,
                                          unsigned short* __restrict__ wl) {
  __shared__ float tile[32][33];
  const int h0 = blockIdx.x * 32;
  const int i0 = blockIdx.y * 32;
  const int c = threadIdx.x & 31;
  const int r4 = threadIdx.x >> 5;
#pragma unroll
  for (int s = 0; s < 4; ++s) {
    const int r = r4 + s * 8;
    tile[r][c] = W1[(long)(i0 + r) * Hsz + h0 + c];
  }
  __syncthreads();
#pragma unroll
  for (int s = 0; s < 4; ++s) {
    const int hr = r4 + s * 8;
    const float v = tile[c][hr];
    const unsigned short hh = f2bf(v);
    wh[(long)(h0 + hr) * Isz + i0 + c] = hh;
    wl[(long)(h0 + hr) * Isz + i0 + c] = f2bf(v - bf2f(hh));
  }
}

// ---- kernel 3: fused GEMM1 (split-bf16x3, 32x32x16 MFMA) + LIF scan ----
// grid (8 hblk, 64 b), 256 threads = 4 waves (2M x 2N); wave tile 128x128.
__global__ __launch_bounds__(256, 1) void gemm1_scan_kernel(
    const unsigned short* __restrict__ xh, const unsigned short* __restrict__ xl,
    const unsigned short* __restrict__ wth, const unsigned short* __restrict__ wtl,
    const float* __restrict__ b1, float* __restrict__ spk) {
  __shared__ __align__(16) unsigned short lds[LDS_USHORTS];  // 133.1KB

  const int tid = threadIdx.x;
  const int l = tid & 63;
  const int w = tid >> 6;
  const int wm = w >> 1;  // 0..1 (M: t rows)
  const int wn = w & 1;   // 0..1 (N: h cols)
  const int b = blockIdx.y;
  const int hb = blockIdx.x * 256;

  // --- staging source addressing (linear LDS dest + inverse-swizzled source) ---
  // LDS row = 32 ushort = 64B = 4 chunks of 16B; stored chunk' = chunk ^ ((row>>1)&3)
  const int srow = tid >> 2;                          // 0..63 (row within 64-row slab)
  const int gch8 = ((tid & 3) ^ ((tid >> 3) & 3)) * 8;
  const unsigned short* gAh = xh + (long)(b * Tsz + srow) * Isz + gch8;
  const unsigned short* gAl = xl + (long)(b * Tsz + srow) * Isz + gch8;
  const unsigned short* gBh = wth + (long)(hb + srow) * Isz + gch8;
  const unsigned short* gBl = wtl + (long)(hb + srow) * Isz + gch8;

  // one STG = 4 global_load_lds (4 vmcnt events), stages a full 256x32 region
#define STG(OFF, G, KT) do {                                                              \
    unsigned short* d_ = lds + ((KT) & 1) * BUFEL + (OFF) + tid * 8;                      \
    __builtin_amdgcn_global_load_lds(GPTR((G) + (long)(KT) * BK), SPTR(d_), 16, 0, 0);    \
    __builtin_amdgcn_global_load_lds(GPTR((G) + 64 * Isz + (long)(KT) * BK), SPTR(d_ + 2048), 16, 0, 0); \
    __builtin_amdgcn_global_load_lds(GPTR((G) + 128 * Isz + (long)(KT) * BK), SPTR(d_ + 4096), 16, 0, 0); \
    __builtin_amdgcn_global_load_lds(GPTR((G) + 192 * Isz + (long)(KT) * BK), SPTR(d_ + 6144), 16, 0, 0); \
  } while (0)

  // --- fragment read addressing (swizzled): row = {wm,wn}*128 + {mi,ni}*32 + (l&31)
  const int lr = l & 31;
  const int swzf = (l >> 1) & 3;
  const int chK0 = (((l >> 5)) ^ swzf) * 8;      // ks=0 chunk
  const int chK1 = ((2 + (l >> 5)) ^ swzf) * 8;  // ks=1 chunk
  const int abase = (wm * 128 + lr) * 32;
  const int bbase = (wn * 128 + lr) * 32;

  f32x16 acc[4][4];
#pragma unroll
  for (int i = 0; i < 4; ++i)
#pragma unroll
    for (int j = 0; j < 4; ++j) acc[i][j] = (f32x16)(0.f);

#define MM(MI, NI, AF, BF) \
  acc[MI][NI] = __builtin_amdgcn_mfma_f32_32x32x16_bf16(AF, BF, acc[MI][NI], 0, 0, 0)

#define BAR() __builtin_amdgcn_s_barrier()
#define SBAR() __builtin_amdgcn_sched_barrier(0)
#define WAITLGKM(N) do { asm volatile("s_waitcnt lgkmcnt(" #N ")" ::: "memory"); SBAR(); } while (0)

  // --- prologue: stage tile 0 fully; wait AH,BH(0) (own) + barrier => all landed ---
  STG(AH_OFF, gAh, 0);
  STG(BH_OFF, gBh, 0);
  STG(AL_OFF, gAl, 0);
  STG(BL_OFF, gBl, 0);
  asm volatile("s_waitcnt vmcnt(8)" ::: "memory");  // AH,BH(0) landed; AL,BL(0) in flight
  BAR();

  s16x8 Ah0[4], Ah1[4], Al0[4], Al1[4], Bh0[4], Bh1[4], Bl0[4], Bl1[4];

  for (int kt = 0; kt < NKT; ++kt) {
    const unsigned short* p = lds + (kt & 1) * BUFEL;
    const bool st = (kt + 1) < NKT;

    // ===== P1: read Ah,Bh(kt) in 2 pinned groups; stage AH,BH(kt+1); 32 MFMA hihi =====
    // entry invariant: AH,BH(kt) landed for ALL waves (prev vmcnt+BAR pair)
#pragma unroll
    for (int mi = 0; mi < 4; ++mi) Ah0[mi] = *(const s16x8*)(p + AH_OFF + abase + mi * 1024 + chK0);
#pragma unroll
    for (int ni = 0; ni < 4; ++ni) Bh0[ni] = *(const s16x8*)(p + BH_OFF + bbase + ni * 1024 + chK0);
    SBAR();  // pin group 1 (8 ds_reads) before group 2
#pragma unroll
    for (int mi = 0; mi < 4; ++mi) Ah1[mi] = *(const s16x8*)(p + AH_OFF + abase + mi * 1024 + chK1);
#pragma unroll
    for (int ni = 0; ni < 4; ++ni) Bh1[ni] = *(const s16x8*)(p + BH_OFF + bbase + ni * 1024 + chK1);
    if (st) { STG(AH_OFF, gAh, kt + 1); STG(BH_OFF, gBh, kt + 1); }
    WAITLGKM(8);  // group 1 (Ah0,Bh0) in-order complete
    __builtin_amdgcn_s_setprio(1);
#pragma unroll
    for (int mi = 0; mi < 4; ++mi)
#pragma unroll
      for (int ni = 0; ni < 4; ++ni) MM(mi, ni, Ah0[mi], Bh0[ni]);
    WAITLGKM(0);  // group 2 complete (hidden under the 16 MFMAs above)
#pragma unroll
    for (int mi = 0; mi < 4; ++mi)
#pragma unroll
      for (int ni = 0; ni < 4; ++ni) MM(mi, ni, Ah1[mi], Bh1[ni]);
    __builtin_amdgcn_s_setprio(0);
    // outstanding: AL,BL(kt)[8 oldest] + AH,BH(kt+1)[8 if st]; P2 reads AL,BL(kt)
    if (st) asm volatile("s_waitcnt vmcnt(8)" ::: "memory");
    else    asm volatile("s_waitcnt vmcnt(0)" ::: "memory");  // kt=31: only ALBL(31) out
    BAR();  // cross-wave: ALL waves' AL,BL(kt) now landed -> P2 reads are safe

    // ===== P2: read Al,Bl(kt) in 2 pinned groups; stage AL,BL(kt+1); 64 MFMA =====
#pragma unroll
    for (int ni = 0; ni < 4; ++ni) {
      Bl0[ni] = *(const s16x8*)(p + BL_OFF + bbase + ni * 1024 + chK0);
      Bl1[ni] = *(const s16x8*)(p + BL_OFF + bbase + ni * 1024 + chK1);
    }
    SBAR();  // pin group 1 (Bl, 8 reads) before group 2 (Al)
#pragma unroll
    for (int mi = 0; mi < 4; ++mi) {
      Al0[mi] = *(const s16x8*)(p + AL_OFF + abase + mi * 1024 + chK0);
      Al1[mi] = *(const s16x8*)(p + AL_OFF + abase + mi * 1024 + chK1);
    }
    if (st) { STG(AL_OFF, gAl, kt + 1); STG(BL_OFF, gBl, kt + 1); }
    WAITLGKM(8);  // Bl group complete
    __builtin_amdgcn_s_setprio(1);
    // hilo: Ah x Bl (Al reads drain underneath)
#pragma unroll
    for (int mi = 0; mi < 4; ++mi)
#pragma unroll
      for (int ni = 0; ni < 4; ++ni) MM(mi, ni, Ah0[mi], Bl0[ni]);
#pragma unroll
    for (int mi = 0; mi < 4; ++mi)
#pragma unroll
      for (int ni = 0; ni < 4; ++ni) MM(mi, ni, Ah1[mi], Bl1[ni]);
    WAITLGKM(0);  // Al group complete
    // lohi: Al x Bh
#pragma unroll
    for (int mi = 0; mi < 4; ++mi)
#pragma unroll
      for (int ni = 0; ni < 4; ++ni) MM(mi, ni, Al0[mi], Bh0[ni]);
#pragma unroll
    for (int mi = 0; mi < 4; ++mi)
#pragma unroll
      for (int ni = 0; ni < 4; ++ni) MM(mi, ni, Al1[mi], Bh1[ni]);
    __builtin_amdgcn_s_setprio(0);
    // outstanding: AH,BH(kt+1)[8 oldest] + AL,BL(kt+1)[8]; next P1 reads AH,BH(kt+1)
    asm volatile("s_waitcnt vmcnt(8)" ::: "memory");  // kt=31: 0 outstanding, no-op
    BAR();  // cross-wave: AH,BH(kt+1) landed for all waves
  }

  // ---- LIF scan: 2 rounds x 128 timesteps through LDS (padded stride) ----
  __syncthreads();
  float* scanbuf = reinterpret_cast<float*>(lds);  // [128][260] f32
  float memv = 0.f;
  int fired = 0;
  const float b1v = b1[hb + tid];

  for (int rnd = 0; rnd < 2; ++rnd) {
    if (wm == rnd) {
      // C/D 32x32: col(h) = l&31, row(t) = (r&3) + 8*(r>>2) + 4*(l>>5)
#pragma unroll
      for (int mi = 0; mi < 4; ++mi)
#pragma unroll
        for (int ni = 0; ni < 4; ++ni) {
          const int col = wn * 128 + ni * 32 + lr;
#pragma unroll
          for (int r = 0; r < 16; ++r) {
            const int trow = mi * 32 + (r & 3) + 8 * (r >> 2) + 4 * (l >> 5);
            scanbuf[trow * SCAN_STRIDE + col] = acc[mi][ni][r];
          }
        }
    }
    __syncthreads();
    {
      for (int t = 0; t < 128; ++t) {
        const float c = scanbuf[t * SCAN_STRIDE + tid] + b1v;
        memv = memv * 0.9f + c * 0.1f;
        fired = memv > 1.0f;
        if (fired) memv = 0.f;
      }
    }
    __syncthreads();
  }
  spk[(long)b * Hsz + hb + tid] = fired ? 1.0f : 0.0f;
}

// ------- kernel 4: out = spk @ W2 + b2, exploiting spike sparsity -------
__global__ void gemm2_kernel(const float* __restrict__ spk, const float* __restrict__ W2,
                             const float* __restrict__ b2, float* __restrict__ out) {
  __shared__ int s_cnt[256];
  __shared__ int s_off[257];
  __shared__ int s_list[Hsz];
  const int b = blockIdx.x;
  const int tid = threadIdx.x;
  int hs[8];
  int c = 0;
#pragma unroll
  for (int e = 0; e < 8; ++e) {
    const int h = tid * 8 + e;
    if (spk[(long)b * Hsz + h] > 0.5f) hs[c++] = h;
  }
  s_cnt[tid] = c;
  __syncthreads();
  if (tid == 0) {
    int s = 0;
    for (int i = 0; i < 256; ++i) { s_off[i] = s; s += s_cnt[i]; }
    s_off[256] = s;
  }
  __syncthreads();
  {
    const int base = s_off[tid];
    for (int i = 0; i < c; ++i) s_list[base + i] = hs[i];
  }
  __syncthreads();
  const int total = s_off[256];
#pragma unroll
  for (int q = 0; q < 4; ++q) {
    const int o = q * 256 + tid;
    float v = b2[o];
    for (int i = 0; i < total; ++i) v += W2[(long)s_list[i] * Osz + o];
    out[(long)b * Osz + o] = v;
  }
}

extern "C" void kernel_launch(void* const* d_in, const int* in_sizes, int n_in,
                              void* d_out, int out_size, void* d_ws, size_t ws_size,
                              hipStream_t stream) {
  const float* x = (const float*)d_in[0];
  const float* W1 = (const float*)d_in[1];
  const float* b1 = (const float*)d_in[2];
  const float* W2 = (const float*)d_in[3];
  const float* b2 = (const float*)d_in[4];
  float* out = (float*)d_out;

  unsigned short* xh = (unsigned short*)d_ws;           // [16384][1024] bf16
  unsigned short* xl = xh + (long)Bsz * Tsz * Isz;
  unsigned short* wh = xl + (long)Bsz * Tsz * Isz;      // [2048][1024] (W1^T)
  unsigned short* wl = wh + (long)Hsz * Isz;
  float* spk = (float*)(wl + (long)Hsz * Isz);          // [64][2048]

  split_x_kernel<<<(Bsz * Tsz * Isz) / (256 * 4), 256, 0, stream>>>(x, xh, xl);
  w1_transpose_split_kernel<<<dim3(Hsz / 32, Isz / 32), 256, 0, stream>>>(W1, wh, wl);
  gemm1_scan_kernel<<<dim3(8, 64), 256, 0, stream>>>(xh, xl, wh, wl, b1, spk);
  gemm2_kernel<<<Bsz, 256, 0, stream>>>(spk, W2, b2, out);
}